// Round 4
// baseline (290.221 us; speedup 1.0000x reference)
//
#include <hip/hip_runtime.h>
#include <hip/hip_bf16.h>
#include <cstdint>
#include <cstddef>

#define B_  64
#define T_  256
#define C_  2048
#define HS_ 128
#define N_  384

typedef __bf16 bf16x8 __attribute__((ext_vector_type(8)));
typedef float  floatx4 __attribute__((ext_vector_type(4)));

__device__ __forceinline__ unsigned short f2bf_rne(float f) {
  union { float f; unsigned int u; } v; v.f = f;
  unsigned int r = v.u + 0x7fffu + ((v.u >> 16) & 1u);
  return (unsigned short)(r >> 16);
}
__device__ __forceinline__ unsigned short f2bf(float f) {
  union { float f; unsigned int u; } v; v.f = f;
  return (unsigned short)((v.u + 0x8000u) >> 16);
}

__device__ __forceinline__ void async_copy16(const void* g, void* l) {
  __builtin_amdgcn_global_load_lds(
      (const __attribute__((address_space(1))) unsigned int*)g,
      (__attribute__((address_space(3))) unsigned int*)l, 16, 0, 0);
}

// ---------------- Weight transpose + bf16 cast: Wt[w*128+h][c] = W_w[c][h] ---
__global__ __launch_bounds__(256) void wt_kernel(
    const float* __restrict__ Wk, const float* __restrict__ Wq,
    const float* __restrict__ Wv, unsigned short* __restrict__ Wt) {
  __shared__ float tile[32][33];
  const int w  = blockIdx.z;
  const int c0 = blockIdx.x * 32;
  const int h0 = blockIdx.y * 32;
  const float* W = (w == 0) ? Wk : (w == 1) ? Wq : Wv;
  const int tx = threadIdx.x & 31, ty = threadIdx.x >> 5;
#pragma unroll
  for (int i = 0; i < 32; i += 8)
    tile[ty + i][tx] = W[(size_t)(c0 + ty + i) * HS_ + h0 + tx];
  __syncthreads();
#pragma unroll
  for (int i = 0; i < 32; i += 8) {
    int hh = ty + i, cc = tx;
    Wt[(size_t)(w * HS_ + h0 + hh) * C_ + c0 + cc] = f2bf_rne(tile[cc][hh]);
  }
}

// ---------------- QKV GEMM: BM=32 x BN=384 (full N), BK=32 ------------------
// Supply-bound model (rounds 0/3: per-block K-step invariant at ~6400 cy,
// independent of blocks/CU => per-CU byte supply is the cap). Cut bytes:
// A (fp32, the slow L3/HBM pool) is read EXACTLY ONCE (BN = full N), B
// re-reads come from L2 (Wt = 1.5 MB, L2-resident). 256 thr / 4 waves,
// each wave owns a 32x96 n-slice; grid = 512 = 2 blocks/CU.
// Round-0-proven machinery kept: cooperative coalesced A staging ->
// in-register f2bf -> padded As; B via global_load_lds with chunk-xor
// swizzle; ONE barrier per K-step.
__global__ __launch_bounds__(256, 2) void qkv_gemm(
    const float* __restrict__ X, const unsigned short* __restrict__ Wt,
    unsigned short* __restrict__ kqv, unsigned short* __restrict__ vT) {
  __shared__ unsigned short As[2][32 * 40];   // 2 x 2.5 KB (pad 40)
  __shared__ unsigned short Bs[2][384 * 32];  // 2 x 24 KB (chunk-swizzled)

  const int tid  = threadIdx.x;
  const int wave = tid >> 6, lane = tid & 63;
  const int quad = lane >> 4, l16 = lane & 15;

  const int m0 = blockIdx.x * 32;
  const int wn = wave * 96;          // wave's n-slice

  // B DMA: 384 rows x 4 chunks(16B) = 1536 slots = 6/thread.
  // LDS stays linear (slot s at byte s*16); the source chunk is xor-swizzled
  // so the read side can de-swizzle conflict-spread.
  int bn[6], bc[6], bdst[6];
#pragma unroll
  for (int r = 0; r < 6; ++r) {
    int s = r * 256 + tid;
    int n = s >> 2, c = s & 3;
    bn[r] = n; bc[r] = c ^ (n & 3);
    bdst[r] = (r * 256 + wave * 64) * 8;   // wave-uniform base (shorts)
  }

  // A staging: 32 rows x 8 float4-chunks = 256 slots = 1/thread (coalesced:
  // 8 consecutive threads cover one 128B row segment).
  const int arow = tid >> 3;   // 0..31
  const int achk = tid & 7;    // float4 chunk in the 32-wide K-step

  // ---- prologue: B_0 DMA + A_0 load
#pragma unroll
  for (int r = 0; r < 6; ++r)
    async_copy16(Wt + (size_t)bn[r] * C_ + bc[r] * 8, &Bs[0][bdst[r]]);
  float4 av = *(const float4*)(X + (size_t)(m0 + arow) * C_ + achk * 4);

  floatx4 acc[2][6] = {};

  for (int k = 0; k < 64; ++k) {
    const int cur = k & 1, nxt = cur ^ 1;
    // ---- convert & store A_k
    {
      ushort4 b4;
      b4.x = f2bf(av.x); b4.y = f2bf(av.y);
      b4.z = f2bf(av.z); b4.w = f2bf(av.w);
      *(ushort4*)&As[cur][arow * 40 + achk * 4] = b4;
    }
    __syncthreads();   // As[cur] stores + Bs[cur] DMA now visible

    // ---- issue next K-step's loads (full iteration of latency cover)
    if (k < 63) {
      const int kn = (k + 1) * 32;
#pragma unroll
      for (int r = 0; r < 6; ++r)
        async_copy16(Wt + (size_t)bn[r] * C_ + kn + bc[r] * 8, &Bs[nxt][bdst[r]]);
      av = *(const float4*)(X + (size_t)(m0 + arow) * C_ + kn + achk * 4);
    }

    // ---- compute: 12 MFMAs/wave (2m x 6n), 12 independent chains
    bf16x8 af[2], bfv[6];
#pragma unroll
    for (int mt = 0; mt < 2; ++mt)
      af[mt] = *(const bf16x8*)&As[cur][(mt * 16 + l16) * 40 + quad * 8];
#pragma unroll
    for (int nt = 0; nt < 6; ++nt) {
      int n = wn + nt * 16 + l16;
      int c = quad ^ (n & 3);
      bfv[nt] = *(const bf16x8*)&Bs[cur][n * 32 + c * 8];
    }
#pragma unroll
    for (int mt = 0; mt < 2; ++mt)
#pragma unroll
      for (int nt = 0; nt < 6; ++nt)
        acc[mt][nt] = __builtin_amdgcn_mfma_f32_16x16x32_bf16(
            af[mt], bfv[nt], acc[mt][nt], 0, 0, 0);
  }

  // ---- epilogue: C/D layout col=lane&15, row=quad*4+reg
#pragma unroll
  for (int mt = 0; mt < 2; ++mt)
#pragma unroll
    for (int nt = 0; nt < 6; ++nt)
#pragma unroll
      for (int r = 0; r < 4; ++r) {
        int row = m0 + mt * 16 + quad * 4 + r;
        int col = wn + nt * 16 + l16;
        unsigned short us = f2bf(acc[mt][nt][r]);
        kqv[(size_t)row * N_ + col] = us;
        if (col >= 256) {   // V region -> also store transposed
          int bb = row >> 8, tt = row & 255;
          vT[(size_t)bb * HS_ * T_ + (size_t)(col - 256) * T_ + tt] = us;
        }
      }
}

// ---------------- Attention: 4 parity waves per t-tile ----------------------
// One t-tile per block, grid (16, 64) = 1024 blocks = 4/CU, 16 waves/CU.
// Wave par handles s-tiles st with st%4==par, packed densely in its private
// P buffer (max 4 tiles -> 72-col pad). Partial O (unnormalized) + partial
// rowsum from parities 1..3 combined in LDS by parity 0. Serial QK^T chain
// per wave drops to <=4 iterations (was <=8).
__global__ __launch_bounds__(256) void attn_kernel(
    const unsigned short* __restrict__ kqv, const unsigned short* __restrict__ vT,
    float* __restrict__ out) {
  __shared__ unsigned short P[4][16 * 72];   // 9 KB, per-parity packed P
  __shared__ float Olds[3][16][132];         // 25.3 KB (pad 132)
  __shared__ float rs1[3][16];

  const int tid  = threadIdx.x;
  const int par  = tid >> 6;                 // wave index = parity 0..3
  const int lane = tid & 63;
  const int quad = lane >> 4, l16 = lane & 15;
  const int tt = blockIdx.x;                 // 0..15
  const int b  = blockIdx.y;
  const int t0 = tt * 16;
  const float scale = 0.022097086912079612f; // 2048^-0.5
  const unsigned short* kq = kqv + (size_t)b * T_ * N_;

  // k fragments (A operand), rows t0..t0+15
  bf16x8 kf[4];
#pragma unroll
  for (int ks = 0; ks < 4; ++ks)
    kf[ks] = *(const bf16x8*)&kq[(size_t)(t0 + l16) * N_ + ks * 32 + quad * 8];

  const int n_my = (tt >= par) ? (((tt - par) >> 2) + 1) : 0;  // <= 4
  const int npad = (n_my + 1) & ~1;                            // even, <= 4

  float rsum[4] = {0.f, 0.f, 0.f, 0.f};

  // ---- S = k q^T over my s-tiles, exp+mask, pack into P
  for (int j = 0; j < n_my; ++j) {
    const int st = par + 4 * j;
    bf16x8 qf[4];
#pragma unroll
    for (int ks = 0; ks < 4; ++ks)
      qf[ks] = *(const bf16x8*)&kq[(size_t)(st * 16 + l16) * N_ + HS_ + ks * 32 + quad * 8];
    floatx4 a = {};
#pragma unroll
    for (int ks = 0; ks < 4; ++ks)
      a = __builtin_amdgcn_mfma_f32_16x16x32_bf16(kf[ks], qf[ks], a, 0, 0, 0);
    const int scol = st * 16 + l16;
#pragma unroll
    for (int r = 0; r < 4; ++r) {
      int trow = t0 + quad * 4 + r;
      float p = (scol <= trow) ? __expf(a[r] * scale) : 0.f;
      rsum[r] += p;
      P[par][(quad * 4 + r) * 72 + j * 16 + l16] = f2bf(p);
    }
  }
  if (npad > n_my) {  // zero-fill the odd tail tile
#pragma unroll
    for (int r = 0; r < 4; ++r)
      P[par][(quad * 4 + r) * 72 + n_my * 16 + l16] = 0;
  }
  // row sums: reduce across the 16 lanes of each quad
#pragma unroll
  for (int m = 1; m < 16; m <<= 1)
#pragma unroll
    for (int r = 0; r < 4; ++r)
      rsum[r] += __shfl_xor(rsum[r], m, 64);

  // ---- O_partial = P @ V over packed k-steps
  floatx4 oacc[8] = {};
  const unsigned short* vb = vT + (size_t)b * HS_ * T_;
  const int nks = npad >> 1;             // <= 2
  const int sb_off = (quad >> 1);        // which packed 16-tile inside 32-k
  const int sb_lo  = (quad & 1) * 8;
  for (int ks2 = 0; ks2 < nks; ++ks2) {
    const int jt = 2 * ks2 + sb_off;
    const int st = par + 4 * jt;         // tile >= n_my is zero-padded in P
    const int sbase = st * 16 + sb_lo;
    bf16x8 pa = *(const bf16x8*)&P[par][l16 * 72 + ks2 * 32 + quad * 8];
#pragma unroll
    for (int nt = 0; nt < 8; ++nt) {
      bf16x8 bv = *(const bf16x8*)&vb[(size_t)(nt * 16 + l16) * T_ + sbase];
      oacc[nt] = __builtin_amdgcn_mfma_f32_16x16x32_bf16(pa, bv, oacc[nt], 0, 0, 0);
    }
  }

  // ---- combine partials: parities 1..3 write, parity 0 sums + normalizes
  if (par > 0) {
#pragma unroll
    for (int nt = 0; nt < 8; ++nt)
#pragma unroll
      for (int r = 0; r < 4; ++r)
        Olds[par - 1][quad * 4 + r][nt * 16 + l16] = oacc[nt][r];
    if (l16 == 0) {
#pragma unroll
      for (int r = 0; r < 4; ++r) rs1[par - 1][quad * 4 + r] = rsum[r];
    }
  }
  __syncthreads();
  if (par == 0) {
    float inv[4];
#pragma unroll
    for (int r = 0; r < 4; ++r) {
      int row = quad * 4 + r;
      inv[r] = 1.f / (rsum[r] + rs1[0][row] + rs1[1][row] + rs1[2][row]);
    }
    float* ob = out + ((size_t)b * T_ + t0) * HS_;
#pragma unroll
    for (int nt = 0; nt < 8; ++nt)
#pragma unroll
      for (int r = 0; r < 4; ++r) {
        int row = quad * 4 + r;
        int col = nt * 16 + l16;
        ob[(size_t)row * HS_ + col] =
            (oacc[nt][r] + Olds[0][row][col] + Olds[1][row][col] + Olds[2][row][col]) * inv[r];
      }
  }
}

extern "C" void kernel_launch(void* const* d_in, const int* in_sizes, int n_in,
                              void* d_out, int out_size, void* d_ws, size_t ws_size,
                              hipStream_t stream) {
  const float* x  = (const float*)d_in[0];
  const float* Wk = (const float*)d_in[1];
  const float* Wq = (const float*)d_in[2];
  const float* Wv = (const float*)d_in[3];
  float* out = (float*)d_out;

  char* ws = (char*)d_ws;
  unsigned short* Wt  = (unsigned short*)(ws);                        // 1.5 MB
  unsigned short* kqv = (unsigned short*)(ws + 1572864);              // 12 MB
  unsigned short* vT  = (unsigned short*)(ws + 1572864 + 12582912);   // 4 MB

  hipLaunchKernelGGL(wt_kernel, dim3(64, 4, 3), dim3(256), 0, stream, Wk, Wq, Wv, Wt);
  hipLaunchKernelGGL(qkv_gemm, dim3(512), dim3(256), 0, stream, x, Wt, kqv, vT);
  hipLaunchKernelGGL(attn_kernel, dim3(16, 64), dim3(256), 0, stream, kqv, vT, out);
}